// Round 3
// baseline (896.391 us; speedup 1.0000x reference)
//
#include <hip/hip_runtime.h>
#include <hip/hip_bf16.h>

#define NT 256
#define TB 8   // batch elements per block

typedef unsigned short u16;
typedef unsigned int u32;

__device__ __forceinline__ float bf2f(u16 u) {
  union { u32 i; float f; } v; v.i = ((u32)u) << 16; return v.f;
}
__device__ __forceinline__ float2 up2(u32 p) {
  union { u32 i; float f; } a, b;
  a.i = p << 16; b.i = p & 0xffff0000u;
  return make_float2(a.f, b.f);
}
__device__ __forceinline__ u16 f2bf(float f) {
  union { float f; u32 i; } v; v.f = f;
  u32 r = v.i + 0x7fffu + ((v.i >> 16) & 1u);  // round-to-nearest-even
  return (u16)(r >> 16);
}
__device__ __forceinline__ u32 pk2(float a, float b) {
  return (u32)f2bf(a) | ((u32)f2bf(b) << 16);
}
__device__ __forceinline__ void up8(uint4 u, float* d) {
  float2 f;
  f = up2(u.x); d[0]=f.x; d[1]=f.y;
  f = up2(u.y); d[2]=f.x; d[3]=f.y;
  f = up2(u.z); d[4]=f.x; d[5]=f.y;
  f = up2(u.w); d[6]=f.x; d[7]=f.y;
}

// prep: block-independent s1bp[a][f] = s1_b + arep @ s1w[:,128:].T  -> ws (f32)
__global__ void prep_kernel(const float* __restrict__ emb, const int* __restrict__ act_idx,
                            const int* __restrict__ act_cnt, const float* __restrict__ s1w,
                            const float* __restrict__ s1b, float* __restrict__ ws) {
  __shared__ float s_arep[20][64];
  int t = threadIdx.x;
  for (int o = t; o < 20 * 64; o += 256) {
    int a = o >> 6, k = o & 63;
    int cnt = act_cnt[a];
    float sum = 0.f;
#pragma unroll
    for (int j = 0; j < 4; ++j)
      if (j < cnt) sum += emb[act_idx[a * 4 + j] * 64 + k];
    s_arep[a][k] = sum / (float)(cnt > 1 ? cnt : 1);
  }
  __syncthreads();
  for (int o = t; o < 20 * 64; o += 256) {
    int a = o >> 6, f = o & 63;
    const float* wr = s1w + f * 192 + 128;
    float acc = s1b[f];
#pragma unroll 8
    for (int k = 0; k < 64; ++k) acc += s_arep[a][k] * wr[k];
    ws[o] = acc;
  }
}

struct SW1 {                       // attention window
  u16 x_ah[64 * 72];               // x (P0b-P1), then ah (P4-P5a)
  u16 qkv[64 * 200];               // [es][f] f: 0..63 q | 64..127 k | 128..191 v
  float sc[8 * 4 * 8 * 9];         // probs [(e*4+h)*8+q]*9+kk
};
struct SW2 {                       // post-attention window (overlays qkv+sc)
  u16 x_ah[64 * 72];               // keeps ah alive through P5a
  float hx[TB][68];
  float g1[TB][68];
  float hand[TB][68];
  float g[TB][36];
  float ctx[TB][132];
  float ctx2[TB][132];
  float s1a[TB][68];
  float w2t[64][36];               // w2t[j][m] = s2w[m][j]
};

__global__ __launch_bounds__(NT, 3) void policy_fused(
    const int* __restrict__ hand_cards, const float* __restrict__ game_state,
    const int* __restrict__ hand_size, const int* __restrict__ num_valid,
    const float* __restrict__ emb, const float* __restrict__ ipw, const float* __restrict__ ipb,
    const float* __restrict__ ow, const float* __restrict__ ob,
    const float* __restrict__ g1w, const float* __restrict__ g1b,
    const float* __restrict__ g2w, const float* __restrict__ g2b,
    const float* __restrict__ c1w, const float* __restrict__ c1b,
    const float* __restrict__ c2w, const float* __restrict__ c2b,
    const float* __restrict__ s1w, const float* __restrict__ s2w,
    const float* __restrict__ s2b, const float* __restrict__ s3w,
    const float* __restrict__ s3b, const float* __restrict__ ws_s1bp,
    float* __restrict__ out)
{
  __shared__ union { SW1 w1; SW2 w2; } S;
  __shared__ int   s_cards[64];
  __shared__ float s_invlen[TB];
  __shared__ float s_gs[TB][12];
  __shared__ float s_s1bp[20][65];

  const int t = threadIdx.x;
  const int base = blockIdx.x * TB;
  const int lw = t & 63, wv = t >> 6;
  const int e8 = lw >> 3, kc = lw & 7;

  // ---- P0a ----
  if (t < 64) s_cards[t] = hand_cards[base * 8 + t];
  if (t < TB) { int hs = hand_size[base + t]; s_invlen[t] = 1.0f / (float)(hs > 1 ? hs : 1); }
  if (t >= 64 && t < 64 + TB * 12) {
    int i = t - 64; s_gs[i / 12][i % 12] = game_state[(base + i / 12) * 12 + i % 12];
  }
  for (int o = t; o < 20 * 64; o += NT) s_s1bp[o >> 6][o & 63] = ws_s1bp[o];
  __syncthreads();

  // ---- P0b: gather x = emb[cards] -> bf16 LDS ----
  {
    int es = t >> 2, k0 = (t & 3) * 16;
    const float* src = emb + s_cards[es] * 64 + k0;
    float4 v0 = *(const float4*)(src);
    float4 v1 = *(const float4*)(src + 4);
    float4 v2 = *(const float4*)(src + 8);
    float4 v3 = *(const float4*)(src + 12);
    uint4 pa = make_uint4(pk2(v0.x,v0.y), pk2(v0.z,v0.w), pk2(v1.x,v1.y), pk2(v1.z,v1.w));
    uint4 pb = make_uint4(pk2(v2.x,v2.y), pk2(v2.z,v2.w), pk2(v3.x,v3.y), pk2(v3.z,v3.w));
    *(uint4*)(S.w1.x_ah + es * 72 + k0) = pa;
    *(uint4*)(S.w1.x_ah + es * 72 + k0 + 8) = pb;
  }
  __syncthreads();

  // ---- P1: qkv = x @ ipw.T + ipb (x in regs, wave-uniform weight rows) ----
  {
    float xr[64];
    const u16* xrow = S.w1.x_ah + lw * 72;
#pragma unroll
    for (int k8 = 0; k8 < 8; ++k8) up8(*(const uint4*)(xrow + k8 * 8), xr + k8 * 8);
    for (int f = wv; f < 192; f += 4) {
      const float* wr = ipw + f * 64;
      float a0 = 0.f, a1 = 0.f, a2 = 0.f, a3 = 0.f;
#pragma unroll
      for (int k = 0; k < 64; k += 4) {
        float4 w4 = *(const float4*)(wr + k);
        a0 += xr[k] * w4.x; a1 += xr[k+1] * w4.y;
        a2 += xr[k+2] * w4.z; a3 += xr[k+3] * w4.w;
      }
      S.w1.qkv[lw * 200 + f] = f2bf(a0 + a1 + a2 + a3 + ipb[f]);
    }
  }
  __syncthreads();

  // ---- P2: masked scaled scores + softmax ----
  {
    int e = t >> 5, h = (t >> 3) & 3, q = t & 7;
    const u16* qrow = S.w1.qkv + (e * 8 + q) * 200 + h * 16;
    float qr[16];
    up8(*(const uint4*)(qrow), qr);
    up8(*(const uint4*)(qrow + 8), qr + 8);
    float sc[8];
#pragma unroll
    for (int kk = 0; kk < 8; ++kk) {
      const u16* krow = S.w1.qkv + (e * 8 + kk) * 200 + 64 + h * 16;
      float kr[16];
      up8(*(const uint4*)(krow), kr);
      up8(*(const uint4*)(krow + 8), kr + 8);
      float a0 = 0.f;
#pragma unroll
      for (int d = 0; d < 16; ++d) a0 += qr[d] * kr[d];
      sc[kk] = (s_cards[e * 8 + kk] != 0) ? a0 * 0.25f : -1e9f;
    }
    float m = sc[0];
#pragma unroll
    for (int kk = 1; kk < 8; ++kk) m = fmaxf(m, sc[kk]);
    float ssum = 0.f;
#pragma unroll
    for (int kk = 0; kk < 8; ++kk) { sc[kk] = __expf(sc[kk] - m); ssum += sc[kk]; }
    float inv = 1.f / ssum;
    float* dst = S.w1.sc + ((e * 4 + h) * 8 + q) * 9;
#pragma unroll
    for (int kk = 0; kk < 8; ++kk) dst[kk] = sc[kk] * inv;
  }
  __syncthreads();

  // ---- P4: ah = attn @ V -> bf16 into x_ah overlay ----
  {
    int es = lw, h = wv;
    int e = es >> 3, q = es & 7;
    const float* pr = S.w1.sc + ((e * 4 + h) * 8 + q) * 9;
    float p[8];
#pragma unroll
    for (int kk = 0; kk < 8; ++kk) p[kk] = pr[kk];
    float acc[16];
#pragma unroll
    for (int d = 0; d < 16; ++d) acc[d] = 0.f;
#pragma unroll
    for (int kk = 0; kk < 8; ++kk) {
      const u16* vrow = S.w1.qkv + (e * 8 + kk) * 200 + 128 + h * 16;
      float vv[16];
      up8(*(const uint4*)(vrow), vv);
      up8(*(const uint4*)(vrow + 8), vv + 8);
#pragma unroll
      for (int d = 0; d < 16; ++d) acc[d] += p[kk] * vv[d];
    }
    uint4 oa = make_uint4(pk2(acc[0],acc[1]), pk2(acc[2],acc[3]), pk2(acc[4],acc[5]), pk2(acc[6],acc[7]));
    uint4 oc = make_uint4(pk2(acc[8],acc[9]), pk2(acc[10],acc[11]), pk2(acc[12],acc[13]), pk2(acc[14],acc[15]));
    *(uint4*)(S.w1.x_ah + es * 72 + h * 16) = oa;
    *(uint4*)(S.w1.x_ah + es * 72 + h * 16 + 8) = oc;
  }
  __syncthreads();

  // ---- P5a: hx = sum_q ah ; g1 MLP ; stage w2t ----
  for (int o = t; o < TB * 64; o += NT) {
    int e = o >> 6, k = o & 63;
    float s = 0.f;
#pragma unroll
    for (int q = 0; q < 8; ++q) s += bf2f(S.w2.x_ah[(e * 8 + q) * 72 + k]);
    S.w2.hx[e][k] = s;
  }
  for (int o = t; o < TB * 64; o += NT) {
    int e = o >> 6, f = o & 63;
    float acc = g1b[f];
#pragma unroll
    for (int k = 0; k < 12; ++k) acc += s_gs[e][k] * g1w[f * 12 + k];
    S.w2.g1[e][f] = fmaxf(acc, 0.f);
  }
  for (int o = t; o < 2048; o += NT) {
    int m = o >> 6, j = o & 63;
    S.w2.w2t[j][m] = s2w[o];
  }
  __syncthreads();

  // ---- P5b: hand_ctx (8e x 8kc split dot) ; g2 MLP ----
  for (int f = wv; f < 64; f += 4) {
    const float* wr = ow + f * 64 + kc;
    const float* hr = &S.w2.hx[e8][kc];
    float p = 0.f;
#pragma unroll
    for (int j = 0; j < 8; ++j) p += hr[8 * j] * wr[8 * j];
    p += __shfl_xor(p, 1); p += __shfl_xor(p, 2); p += __shfl_xor(p, 4);
    if (kc == 0) S.w2.hand[e8][f] = (p + 8.f * ob[f]) * s_invlen[e8];
  }
  for (int f = wv; f < 32; f += 4) {
    const float* wr = g2w + f * 64 + kc;
    const float* gr = &S.w2.g1[e8][kc];
    float p = 0.f;
#pragma unroll
    for (int j = 0; j < 8; ++j) p += gr[8 * j] * wr[8 * j];
    p += __shfl_xor(p, 1); p += __shfl_xor(p, 2); p += __shfl_xor(p, 4);
    if (kc == 0) S.w2.g[e8][f] = fmaxf(p + g2b[f], 0.f);
  }
  __syncthreads();

  // ---- P6: ctx = relu(c1 @ concat(hand, g)) ----
  for (int f = wv; f < 128; f += 4) {
    const float* wr = c1w + f * 96;
    const float* hr = &S.w2.hand[e8][kc];
    const float* gr = &S.w2.g[e8][kc];
    float p = 0.f;
#pragma unroll
    for (int j = 0; j < 8; ++j) p += hr[8 * j] * wr[kc + 8 * j];
#pragma unroll
    for (int j = 0; j < 4; ++j) p += gr[8 * j] * wr[64 + kc + 8 * j];
    p += __shfl_xor(p, 1); p += __shfl_xor(p, 2); p += __shfl_xor(p, 4);
    if (kc == 0) S.w2.ctx[e8][f] = fmaxf(p + c1b[f], 0.f);
  }
  __syncthreads();

  // ---- P7: ctx2 = relu(c2 @ ctx) ----
  for (int f = wv; f < 128; f += 4) {
    const float* wr = c2w + f * 128 + kc;
    const float* xr2 = &S.w2.ctx[e8][kc];
    float p = 0.f;
#pragma unroll
    for (int j = 0; j < 16; ++j) p += xr2[8 * j] * wr[8 * j];
    p += __shfl_xor(p, 1); p += __shfl_xor(p, 2); p += __shfl_xor(p, 4);
    if (kc == 0) S.w2.ctx2[e8][f] = fmaxf(p + c2b[f], 0.f);
  }
  __syncthreads();

  // ---- P8: s1a = ctx2 @ s1w[:,:128].T (bias lives in s1bp) ----
  for (int f = wv; f < 64; f += 4) {
    const float* wr = s1w + f * 192 + kc;
    const float* xr2 = &S.w2.ctx2[e8][kc];
    float p = 0.f;
#pragma unroll
    for (int j = 0; j < 16; ++j) p += xr2[8 * j] * wr[8 * j];
    p += __shfl_xor(p, 1); p += __shfl_xor(p, 2); p += __shfl_xor(p, 4);
    if (kc == 0) S.w2.s1a[e8][f] = p;
  }
  __syncthreads();

  // ---- P9: per-(e,a) scorer ----
  if (t < TB * 20) {
    int e = t / 20, a = t - e * 20;
    int nv = num_valid[0];
    float acc[32];
#pragma unroll
    for (int m = 0; m < 32; ++m) acc[m] = s2b[m];
    for (int j = 0; j < 64; ++j) {
      float hj = fmaxf(S.w2.s1a[e][j] + s_s1bp[a][j], 0.f);
      const float* wrow = &S.w2.w2t[j][0];
#pragma unroll
      for (int m4 = 0; m4 < 32; m4 += 4) {
        float4 w4 = *(const float4*)(wrow + m4);
        acc[m4]   += hj * w4.x; acc[m4+1] += hj * w4.y;
        acc[m4+2] += hj * w4.z; acc[m4+3] += hj * w4.w;
      }
    }
    float sc2 = s3b[0];
#pragma unroll
    for (int m = 0; m < 32; ++m) sc2 += fmaxf(acc[m], 0.f) * s3w[m];
    out[base * 20 + t] = (a < nv) ? sc2 : -1e8f;
  }
}

extern "C" void kernel_launch(void* const* d_in, const int* in_sizes, int n_in,
                              void* d_out, int out_size, void* d_ws, size_t ws_size,
                              hipStream_t stream) {
  (void)in_sizes; (void)n_in; (void)out_size; (void)ws_size;
  float* out = (float*)d_out;
  float* ws = (float*)d_ws;

  hipLaunchKernelGGL(prep_kernel, dim3(1), dim3(256), 0, stream,
                     (const float*)d_in[6], (const int*)d_in[3], (const int*)d_in[4],
                     (const float*)d_in[19], (const float*)d_in[20], ws);
  hipLaunchKernelGGL(policy_fused, dim3(32768 / TB), dim3(NT), 0, stream,
                     (const int*)d_in[0],  (const float*)d_in[1], (const int*)d_in[2],
                     (const int*)d_in[5],
                     (const float*)d_in[6],  (const float*)d_in[7],  (const float*)d_in[8],
                     (const float*)d_in[9],  (const float*)d_in[10],
                     (const float*)d_in[11], (const float*)d_in[12],
                     (const float*)d_in[13], (const float*)d_in[14],
                     (const float*)d_in[15], (const float*)d_in[16],
                     (const float*)d_in[17], (const float*)d_in[18],
                     (const float*)d_in[19], (const float*)d_in[21],
                     (const float*)d_in[22], (const float*)d_in[23],
                     (const float*)d_in[24], ws, out);
}